// Round 12
// baseline (87.388 us; speedup 1.0000x reference)
//
#include <hip/hip_runtime.h>

typedef __bf16 bf16_t;
typedef __bf16 bf16x8 __attribute__((ext_vector_type(8)));
typedef float  f32x4  __attribute__((ext_vector_type(4)));

#define LDR 72  // padded LDS row stride (bf16): 144 B = 9*16B, 16B-aligned rows

__device__ __forceinline__ float bflo(unsigned u){ return __uint_as_float(u << 16); }
__device__ __forceinline__ float bfhi(unsigned u){ return __uint_as_float(u & 0xffff0000u); }
__device__ __forceinline__ void lds_fence(){
    asm volatile("s_waitcnt lgkmcnt(0)" ::: "memory");
    __builtin_amdgcn_sched_barrier(0);
}

// ws layout (bf16 elems): emb_bf[8192] | hw_bf[8192] | w1T[4096] | w2T[4096] | map (64*4 ints)
#define WS_MAP_OFF 24576

// ---------------------------------------------------------------------------
// prep: tables + runtime C/D-map probe.
// ---------------------------------------------------------------------------
__global__ void prep_kernel(const float* __restrict__ emb,
                            const float* __restrict__ gcn_w,
                            const float* __restrict__ lin1_w,
                            const float* __restrict__ lin2_w,
                            bf16_t* __restrict__ ws)
{
    int t = blockIdx.x * 256 + threadIdx.x;     // 0..8191
    bf16_t* emb_bf = ws;
    bf16_t* hw_bf  = ws + 8192;
    bf16_t* w1T    = ws + 16384;
    bf16_t* w2T    = ws + 20480;

    emb_bf[t] = (bf16_t)emb[t];
    int i = t >> 6, j = t & 63;
    float s = 0.f;
    #pragma unroll 8
    for (int k = 0; k < 64; ++k) s += emb[i*64 + k] * gcn_w[k*64 + j];
    hw_bf[t] = (bf16_t)s;
    if (t < 4096){
        int jj = t >> 6, kk = t & 63;           // wT[j*64+k] = w[k*64+j]
        w1T[t] = (bf16_t)lin1_w[kk*64 + jj];
        w2T[t] = (bf16_t)lin2_w[kk*64 + jj];
    }

    if (blockIdx.x == 0){
        __shared__ bf16_t pA[16*32];   // A[i][k]:  k==0 -> i, k==1 -> 1, else 0
        __shared__ bf16_t pB[16*32];   // BT[j][k]: k==0 -> 1, k==1 -> 128*j, else 0
        int tid = threadIdx.x;
        for (int c = tid; c < 512; c += 256){
            int r = c >> 5, k = c & 31;
            pA[c] = (bf16_t)((k == 0) ? (float)r : ((k == 1) ? 1.f : 0.f));
            pB[c] = (bf16_t)((k == 0) ? 1.f : ((k == 1) ? (float)(128*r) : 0.f));
        }
        __syncthreads();
        if (tid < 64){
            int l15 = tid & 15, lg = tid >> 4;
            bf16x8 a  = *reinterpret_cast<const bf16x8*>(&pA[l15*32 + lg*8]);
            bf16x8 bb = *reinterpret_cast<const bf16x8*>(&pB[l15*32 + lg*8]);
            f32x4 acc = (f32x4){0.f,0.f,0.f,0.f};
            acc = __builtin_amdgcn_mfma_f32_16x16x32_bf16(a, bb, acc, 0, 0, 0);
            int* map = (int*)(ws + WS_MAP_OFF);
            #pragma unroll
            for (int r = 0; r < 4; ++r){
                int iv = (int)(acc[r] + 0.5f);          // iv = i + 128*j, exact
                map[tid*4 + r] = (iv & 127) | ((iv >> 7) << 8);  // i | j<<8
            }
        }
    }
}

// ---------------------------------------------------------------------------
// fused: one block per graph, 256 threads, single 18 KB data buffer (bufB is
// h1 -> t -> v -> ef), total LDS ~21.5 KB -> 7 blocks/CU (28 waves).
// P3+4 fused in registers; t overwrites h1 after one barrier.
// ---------------------------------------------------------------------------
__global__ __launch_bounds__(256, 7) void fused_kernel(
    const int*   __restrict__ node_feature,
    const int*   __restrict__ edge_index,
    const float* __restrict__ gcn_b,
    const float* __restrict__ lin1_b,
    const float* __restrict__ lin2_b,
    const float* __restrict__ ln_g,
    const float* __restrict__ ln_b,
    const float* __restrict__ ex_w1,
    const float* __restrict__ ex_b1,
    const float* __restrict__ ex_ln_g,
    const float* __restrict__ ex_ln_b,
    const float* __restrict__ ex_w2,
    const float* __restrict__ ex_b2,
    const bf16_t* __restrict__ ws,
    float* __restrict__ out)
{
    __shared__ __align__(16) bf16_t bufB[128*LDR];     // h1 -> t -> v -> ef
    __shared__ __align__(8)  unsigned char pool[2176]; // early sort scratch / late partials
    __shared__ unsigned char s_nf8[128];
    __shared__ float s_b[320];     // gcn_b | lin1_b | lin2_b | ln_g | ln_b

    // early views (dead after phase 3+4 edge walk)
    unsigned char* s_adj   = pool;                    // [512]
    int*           s_start = (int*)(pool + 512);      // [129]
    int*           s_cur   = (int*)(pool + 1040);     // [128]
    float*         s_dinv  = (float*)(pool + 1552);   // [128]
    // late views (first written in phase 6a, after full barriers)
    float*         s_pm    = (float*)pool;            // [256]
    float*         s_means = (float*)(pool + 1024);   // [64]

    const int tid  = threadIdx.x;
    const int b    = blockIdx.x;
    const int wid  = tid >> 6;
    const int lane = tid & 63;
    const int l15  = lane & 15;
    const int lg   = lane >> 4;
    const long obase = (long)b * 16257;

    const bf16_t* emb_bf = ws;
    const bf16_t* hw_bf  = ws + 8192;
    const bf16_t* w1T    = ws + 16384;
    const bf16_t* w2T    = ws + 20480;

    int mi[4], mj[4];
    {
        const int* map = (const int*)(ws + WS_MAP_OFF);
        #pragma unroll
        for (int r = 0; r < 4; ++r){
            int m = map[lane*4 + r];
            mi[r] = m & 255; mj[r] = m >> 8;
        }
    }

    const int2* ei = reinterpret_cast<const int2*>(edge_index) + b*512;
    int2 e0 = ei[tid];
    int2 e1 = ei[tid + 256];

    // ---- phase 0: node ids, zero counts, biases ----
    if (tid < 128) s_nf8[tid] = (unsigned char)node_feature[b*128 + tid];
    else if (tid < 192){
        int j = tid - 128;
        s_b[j]       = gcn_b[j];
        s_b[64 + j]  = lin1_b[j];
        s_b[128 + j] = lin2_b[j];
        s_b[192 + j] = ln_g[j];
        s_b[256 + j] = ln_b[j];
        s_cur[j] = 0;                           // entries 0..63
    } else {
        s_cur[tid - 192 + 64] = 0;              // entries 64..127
    }
    __syncthreads();

    // ---- phase 1: edge count + h1 gather ----
    atomicAdd(&s_cur[e0.y & 127], 1);
    atomicAdd(&s_cur[e1.y & 127], 1);
    #pragma unroll
    for (int c = tid; c < 1024; c += 256){
        int row = c >> 3, ch = c & 7;
        uint4 vh = reinterpret_cast<const uint4*>(hw_bf + (int)s_nf8[row]*64)[ch];
        reinterpret_cast<uint4*>(&bufB[row*LDR])[ch] = vh;
    }
    __syncthreads();

    // ---- phase 2: wave0 scan (counts->start, dinv, cursor) ----
    if (tid < 64){
        int a0 = s_cur[2*tid], a1 = s_cur[2*tid+1];
        s_dinv[2*tid]   = rsqrtf((float)(a0 + 1));
        s_dinv[2*tid+1] = rsqrtf((float)(a1 + 1));
        int s = a0 + a1;
        #pragma unroll
        for (int d = 1; d < 64; d <<= 1){
            int v = __shfl_up(s, d);
            if (lane >= d) s += v;
        }
        int excl = s - (a0 + a1);
        s_start[2*tid]   = excl;
        s_start[2*tid+1] = excl + a0;
        if (tid == 63) s_start[128] = 512;
        s_cur[2*tid]   = excl;
        s_cur[2*tid+1] = excl + a0;
    }
    __syncthreads();

    // ---- phase 2c: bucket sort edges by dst (from registers) ----
    {
        int pos0 = atomicAdd(&s_cur[e0.y & 127], 1);
        s_adj[pos0] = (unsigned char)(e0.x & 127);
        int pos1 = atomicAdd(&s_cur[e1.y & 127], 1);
        s_adj[pos1] = (unsigned char)(e1.x & 127);
    }
    __syncthreads();

    // ---- phase 3+4 fused: agg in registers (A-frag layout); t = relu(agg@lin1+b1)
    {
        // thread owns rows {wid*32 + fm*16 + l15 : fm=0,1},
        // cols {kk*32 + lg*8 + e : kk=0,1; e=0..7}
        float inner[2][16];
        float dnv[2];
        #pragma unroll
        for (int fm = 0; fm < 2; ++fm)
            #pragma unroll
            for (int f = 0; f < 16; ++f) inner[fm][f] = 0.f;

        #pragma unroll
        for (int fm = 0; fm < 2; ++fm){
            const int row = wid*32 + fm*16 + l15;
            const float dn = s_dinv[row];
            dnv[fm] = dn;
            {   // self loop
                uint4 c0 = *reinterpret_cast<const uint4*>(&bufB[row*LDR + lg*8]);
                uint4 c1 = *reinterpret_cast<const uint4*>(&bufB[row*LDR + 32 + lg*8]);
                inner[fm][0]  += dn * bflo(c0.x); inner[fm][1]  += dn * bfhi(c0.x);
                inner[fm][2]  += dn * bflo(c0.y); inner[fm][3]  += dn * bfhi(c0.y);
                inner[fm][4]  += dn * bflo(c0.z); inner[fm][5]  += dn * bfhi(c0.z);
                inner[fm][6]  += dn * bflo(c0.w); inner[fm][7]  += dn * bfhi(c0.w);
                inner[fm][8]  += dn * bflo(c1.x); inner[fm][9]  += dn * bfhi(c1.x);
                inner[fm][10] += dn * bflo(c1.y); inner[fm][11] += dn * bfhi(c1.y);
                inner[fm][12] += dn * bflo(c1.z); inner[fm][13] += dn * bfhi(c1.z);
                inner[fm][14] += dn * bflo(c1.w); inner[fm][15] += dn * bfhi(c1.w);
            }
            const int st = s_start[row], cn = s_start[row+1] - st;
            for (int k = 0; k < cn; ++k){
                int src = s_adj[st + k];
                float w = s_dinv[src];
                uint4 c0 = *reinterpret_cast<const uint4*>(&bufB[src*LDR + lg*8]);
                uint4 c1 = *reinterpret_cast<const uint4*>(&bufB[src*LDR + 32 + lg*8]);
                inner[fm][0]  += w * bflo(c0.x); inner[fm][1]  += w * bfhi(c0.x);
                inner[fm][2]  += w * bflo(c0.y); inner[fm][3]  += w * bfhi(c0.y);
                inner[fm][4]  += w * bflo(c0.z); inner[fm][5]  += w * bfhi(c0.z);
                inner[fm][6]  += w * bflo(c0.w); inner[fm][7]  += w * bfhi(c0.w);
                inner[fm][8]  += w * bflo(c1.x); inner[fm][9]  += w * bfhi(c1.x);
                inner[fm][10] += w * bflo(c1.y); inner[fm][11] += w * bfhi(c1.y);
                inner[fm][12] += w * bflo(c1.z); inner[fm][13] += w * bfhi(c1.z);
                inner[fm][14] += w * bflo(c1.w); inner[fm][15] += w * bfhi(c1.w);
            }
        }

        // A-frags in registers: af[fm][kk][e] = agg[row][kk*32 + lg*8 + e]
        bf16x8 af[2][2];
        #pragma unroll
        for (int fm = 0; fm < 2; ++fm)
            #pragma unroll
            for (int kk = 0; kk < 2; ++kk)
                #pragma unroll
                for (int e = 0; e < 8; ++e){
                    int col = kk*32 + lg*8 + e;
                    af[fm][kk][e] = (bf16_t)(dnv[fm]*inner[fm][kk*8 + e] + s_b[col]);
                }

        f32x4 acc[2][4];
        #pragma unroll
        for (int fm = 0; fm < 2; ++fm)
            #pragma unroll
            for (int fn = 0; fn < 4; ++fn)
                acc[fm][fn] = (f32x4){0.f,0.f,0.f,0.f};
        #pragma unroll
        for (int fn = 0; fn < 4; ++fn)
            #pragma unroll
            for (int kk = 0; kk < 2; ++kk){
                bf16x8 bfr = *reinterpret_cast<const bf16x8*>(
                    &w1T[(fn*16 + l15)*64 + kk*32 + lg*8]);
                #pragma unroll
                for (int fm = 0; fm < 2; ++fm)
                    acc[fm][fn] = __builtin_amdgcn_mfma_f32_16x16x32_bf16(
                        af[fm][kk], bfr, acc[fm][fn], 0, 0, 0);
            }

        // all cross-wave h1 reads are done; safe to overwrite bufB with t
        __syncthreads();

        #pragma unroll
        for (int fm = 0; fm < 2; ++fm)
            #pragma unroll
            for (int fn = 0; fn < 4; ++fn)
                #pragma unroll
                for (int r = 0; r < 4; ++r){
                    int row = wid*32 + fm*16 + mi[r];
                    int col = fn*16 + mj[r];
                    bufB[row*LDR + col] = (bf16_t)fmaxf(acc[fm][fn][r] + s_b[64 + col], 0.f);
                }
    }
    lds_fence();

    // ---- phase 5 (MFMA): v = t @ lin2 + b2 -> bufB own rows ----
    {
        bf16x8 af[2][2];
        #pragma unroll
        for (int fm = 0; fm < 2; ++fm)
            #pragma unroll
            for (int kk = 0; kk < 2; ++kk)
                af[fm][kk] = *reinterpret_cast<const bf16x8*>(
                    &bufB[(wid*32 + fm*16 + l15)*LDR + kk*32 + lg*8]);
        f32x4 acc[2][4];
        #pragma unroll
        for (int fm = 0; fm < 2; ++fm)
            #pragma unroll
            for (int fn = 0; fn < 4; ++fn)
                acc[fm][fn] = (f32x4){0.f,0.f,0.f,0.f};
        #pragma unroll
        for (int fn = 0; fn < 4; ++fn)
            #pragma unroll
            for (int kk = 0; kk < 2; ++kk){
                bf16x8 bfr = *reinterpret_cast<const bf16x8*>(
                    &w2T[(fn*16 + l15)*64 + kk*32 + lg*8]);
                #pragma unroll
                for (int fm = 0; fm < 2; ++fm)
                    acc[fm][fn] = __builtin_amdgcn_mfma_f32_16x16x32_bf16(
                        af[fm][kk], bfr, acc[fm][fn], 0, 0, 0);
            }
        lds_fence();   // A-frag reads complete before overwriting with v
        #pragma unroll
        for (int fm = 0; fm < 2; ++fm)
            #pragma unroll
            for (int fn = 0; fn < 4; ++fn)
                #pragma unroll
                for (int r = 0; r < 4; ++r){
                    int row = wid*32 + fm*16 + mi[r];
                    int col = fn*16 + mj[r];
                    bufB[row*LDR + col] = (bf16_t)(acc[fm][fn][r] + s_b[128 + col]);
                }
    }
    lds_fence();

    // ---- phase 5b: ef = LN(v + x) row-owner pass (own rows) ----
    {
        const int n  = tid >> 1;
        const int f0 = (tid & 1) << 5;
        const bf16x8* xp = reinterpret_cast<const bf16x8*>(&emb_bf[(int)s_nf8[n]*64 + f0]);
        const bf16x8* rp = reinterpret_cast<const bf16x8*>(&bufB[n*LDR + f0]);
        float vv[32];
        float p1 = 0.f, p2 = 0.f;
        #pragma unroll
        for (int q = 0; q < 4; ++q){
            bf16x8 v8 = rp[q];
            bf16x8 x8 = xp[q];
            #pragma unroll
            for (int e = 0; e < 8; ++e){
                float f = (float)v8[e] + (float)x8[e];
                vv[q*8+e] = f; p1 += f; p2 += f*f;
            }
        }
        p1 += __shfl_xor(p1, 1);
        p2 += __shfl_xor(p2, 1);
        float mean = p1 * 0.015625f;
        float var  = p2 * 0.015625f - mean*mean;
        float rstd = rsqrtf(var + 1e-5f);
        #pragma unroll
        for (int j = 0; j < 32; ++j)
            bufB[n*LDR + f0 + j] = (bf16_t)((vv[j] - mean) * rstd * s_b[192 + f0 + j] + s_b[256 + f0 + j]);
    }
    __syncthreads();   // ef complete; cross-wave readers below

    // ---- phase 6a: per-graph column means of ef ----
    {
        int col = tid & 63, q = tid >> 6;
        float s = 0.f;
        #pragma unroll 8
        for (int r = q*32; r < q*32 + 32; ++r)
            s += (float)bufB[r*LDR + col];
        s_pm[q*64 + col] = s;
    }
    __syncthreads();   // s_pm visible to wave 0; ef stable for P7

    // ---- phase 6b: exit head (wave 0 only; same-wave LDS RAW needs no barrier;
    //      waves 1-3 fall straight through to P7) ----
    if (tid < 64){
        s_means[tid] = (s_pm[tid] + s_pm[64+tid] + s_pm[128+tid] + s_pm[192+tid]) * 0.0078125f;
        float a = ex_b1[lane];
        #pragma unroll 8
        for (int k = 0; k < 64; ++k)
            a += s_means[k] * ex_w1[k*64 + lane];
        float p1 = a, p2 = a*a;
        #pragma unroll
        for (int m = 1; m < 64; m <<= 1){ p1 += __shfl_xor(p1, m); p2 += __shfl_xor(p2, m); }
        float mean = p1 * 0.015625f;
        float var  = p2 * 0.015625f - mean*mean;
        float u = (a - mean) * rsqrtf(var + 1e-5f) * ex_ln_g[lane] + ex_ln_b[lane];
        u = fmaxf(u, 0.f);
        float prod = u * ex_w2[lane];
        #pragma unroll
        for (int m = 1; m < 64; m <<= 1) prod += __shfl_xor(prod, m);
        if (lane == 0) out[obase + 16256] = prod + ex_b2[0];
    }

    // ---- phase 7: scores = ef @ ef^T / 8 (MFMA), scalar triu/tril scatter ----
    {
        bf16x8 af[2][2];
        #pragma unroll
        for (int fm = 0; fm < 2; ++fm)
            #pragma unroll
            for (int kk = 0; kk < 2; ++kk)
                af[fm][kk] = *reinterpret_cast<const bf16x8*>(
                    &bufB[(wid*32 + fm*16 + l15)*LDR + kk*32 + lg*8]);
        f32x4 acc[2][8];
        #pragma unroll
        for (int fm = 0; fm < 2; ++fm)
            #pragma unroll
            for (int fn = 0; fn < 8; ++fn)
                acc[fm][fn] = (f32x4){0.f,0.f,0.f,0.f};
        #pragma unroll
        for (int fn = 0; fn < 8; ++fn)
            #pragma unroll
            for (int kk = 0; kk < 2; ++kk){
                bf16x8 bfr = *reinterpret_cast<const bf16x8*>(
                    &bufB[(fn*16 + l15)*LDR + kk*32 + lg*8]);
                #pragma unroll
                for (int fm = 0; fm < 2; ++fm)
                    acc[fm][fn] = __builtin_amdgcn_mfma_f32_16x16x32_bf16(
                        af[fm][kk], bfr, acc[fm][fn], 0, 0, 0);
            }
        float* ob = out + obase;
        #pragma unroll
        for (int fm = 0; fm < 2; ++fm){
            #pragma unroll
            for (int fn = 0; fn < 8; ++fn){
                #pragma unroll
                for (int r = 0; r < 4; ++r){
                    int i = wid*32 + fm*16 + mi[r];
                    int j = fn*16 + mj[r];
                    if (i != j){
                        float v = acc[fm][fn][r] * 0.125f;
                        int p = (i < j) ? (i*127 - ((i*(i-1)) >> 1) + j - i - 1)
                                        : (8128 + ((i*(i-1)) >> 1) + j);
                        ob[p] = v;
                    }
                }
            }
        }
    }
}

extern "C" void kernel_launch(void* const* d_in, const int* in_sizes, int n_in,
                              void* d_out, int out_size, void* d_ws, size_t ws_size,
                              hipStream_t stream)
{
    const int*   node_feature = (const int*)  d_in[0];
    const int*   edge_index   = (const int*)  d_in[1];
    // d_in[2] = batch_ptr (uniform arange*128, unused)
    const float* emb     = (const float*)d_in[3];
    const float* gcn_w   = (const float*)d_in[4];
    const float* gcn_b   = (const float*)d_in[5];
    const float* lin1_w  = (const float*)d_in[6];
    const float* lin1_b  = (const float*)d_in[7];
    const float* lin2_w  = (const float*)d_in[8];
    const float* lin2_b  = (const float*)d_in[9];
    const float* ln_g    = (const float*)d_in[10];
    const float* ln_b    = (const float*)d_in[11];
    const float* ex_w1   = (const float*)d_in[12];
    const float* ex_b1   = (const float*)d_in[13];
    const float* ex_ln_g = (const float*)d_in[14];
    const float* ex_ln_b = (const float*)d_in[15];
    const float* ex_w2   = (const float*)d_in[16];
    const float* ex_b2   = (const float*)d_in[17];
    bf16_t* ws  = (bf16_t*)d_ws;
    float*  out = (float*)d_out;

    prep_kernel<<<32, 256, 0, stream>>>(emb, gcn_w, lin1_w, lin2_w, ws);
    fused_kernel<<<2048, 256, 0, stream>>>(node_feature, edge_index,
        gcn_b, lin1_b, lin2_b, ln_g, ln_b,
        ex_w1, ex_b1, ex_ln_g, ex_ln_b, ex_w2, ex_b2,
        ws, out);
}

// Round 13
// 61.693 us; speedup vs baseline: 1.4165x; 1.4165x over previous
//
#include <hip/hip_runtime.h>

typedef __bf16 bf16_t;
typedef __bf16 bf16x8 __attribute__((ext_vector_type(8)));
typedef float  f32x4  __attribute__((ext_vector_type(4)));

#define LDR 72  // padded LDS row stride (bf16): 144 B = 9*16B, 16B-aligned rows

__device__ __forceinline__ float bflo(unsigned u){ return __uint_as_float(u << 16); }
__device__ __forceinline__ float bfhi(unsigned u){ return __uint_as_float(u & 0xffff0000u); }
__device__ __forceinline__ void lds_fence(){
    asm volatile("s_waitcnt lgkmcnt(0)" ::: "memory");
    __builtin_amdgcn_sched_barrier(0);
}

// ws layout (bf16 elems): emb_bf[8192] | hw_bf[8192] | w1T[4096] | w2T[4096] | map (64*4 ints)
#define WS_MAP_OFF 24576

// ---------------------------------------------------------------------------
// prep: tables + runtime C/D-map probe.
// ---------------------------------------------------------------------------
__global__ void prep_kernel(const float* __restrict__ emb,
                            const float* __restrict__ gcn_w,
                            const float* __restrict__ lin1_w,
                            const float* __restrict__ lin2_w,
                            bf16_t* __restrict__ ws)
{
    int t = blockIdx.x * 256 + threadIdx.x;     // 0..8191
    bf16_t* emb_bf = ws;
    bf16_t* hw_bf  = ws + 8192;
    bf16_t* w1T    = ws + 16384;
    bf16_t* w2T    = ws + 20480;

    emb_bf[t] = (bf16_t)emb[t];
    int i = t >> 6, j = t & 63;
    float s = 0.f;
    #pragma unroll 8
    for (int k = 0; k < 64; ++k) s += emb[i*64 + k] * gcn_w[k*64 + j];
    hw_bf[t] = (bf16_t)s;
    if (t < 4096){
        int jj = t >> 6, kk = t & 63;           // wT[j*64+k] = w[k*64+j]
        w1T[t] = (bf16_t)lin1_w[kk*64 + jj];
        w2T[t] = (bf16_t)lin2_w[kk*64 + jj];
    }

    if (blockIdx.x == 0){
        __shared__ bf16_t pA[16*32];   // A[i][k]:  k==0 -> i, k==1 -> 1, else 0
        __shared__ bf16_t pB[16*32];   // BT[j][k]: k==0 -> 1, k==1 -> 128*j, else 0
        int tid = threadIdx.x;
        for (int c = tid; c < 512; c += 256){
            int r = c >> 5, k = c & 31;
            pA[c] = (bf16_t)((k == 0) ? (float)r : ((k == 1) ? 1.f : 0.f));
            pB[c] = (bf16_t)((k == 0) ? 1.f : ((k == 1) ? (float)(128*r) : 0.f));
        }
        __syncthreads();
        if (tid < 64){
            int l15 = tid & 15, lg = tid >> 4;
            bf16x8 a  = *reinterpret_cast<const bf16x8*>(&pA[l15*32 + lg*8]);
            bf16x8 bb = *reinterpret_cast<const bf16x8*>(&pB[l15*32 + lg*8]);
            f32x4 acc = (f32x4){0.f,0.f,0.f,0.f};
            acc = __builtin_amdgcn_mfma_f32_16x16x32_bf16(a, bb, acc, 0, 0, 0);
            int* map = (int*)(ws + WS_MAP_OFF);
            #pragma unroll
            for (int r = 0; r < 4; ++r){
                int iv = (int)(acc[r] + 0.5f);          // iv = i + 128*j, exact
                map[tid*4 + r] = (iv & 127) | ((iv >> 7) << 8);  // i | j<<8
            }
        }
    }
}

// ---------------------------------------------------------------------------
// fused: one block per graph, 256 threads, single 18 KB data buffer (bufB is
// h1 -> t -> v -> ef), total LDS ~21.5 KB. launch_bounds(256,4) keeps the
// VGPR cap at 128 (compiler's natural 64, no spills); runtime occupancy is
// then LDS-limited at 7 blocks/CU (28 waves).  [R12 lesson: (256,7) forced
// VGPR=36 -> scratch spills -> FETCH 5->36 MB, dur +42%.]
// ---------------------------------------------------------------------------
__global__ __launch_bounds__(256, 4) void fused_kernel(
    const int*   __restrict__ node_feature,
    const int*   __restrict__ edge_index,
    const float* __restrict__ gcn_b,
    const float* __restrict__ lin1_b,
    const float* __restrict__ lin2_b,
    const float* __restrict__ ln_g,
    const float* __restrict__ ln_b,
    const float* __restrict__ ex_w1,
    const float* __restrict__ ex_b1,
    const float* __restrict__ ex_ln_g,
    const float* __restrict__ ex_ln_b,
    const float* __restrict__ ex_w2,
    const float* __restrict__ ex_b2,
    const bf16_t* __restrict__ ws,
    float* __restrict__ out)
{
    __shared__ __align__(16) bf16_t bufB[128*LDR];     // h1 -> t -> v -> ef
    __shared__ __align__(8)  unsigned char pool[2176]; // early sort scratch / late partials
    __shared__ unsigned char s_nf8[128];
    __shared__ float s_b[320];     // gcn_b | lin1_b | lin2_b | ln_g | ln_b

    // early views (dead after phase 3+4 edge walk)
    unsigned char* s_adj   = pool;                    // [512]
    int*           s_start = (int*)(pool + 512);      // [129]
    int*           s_cur   = (int*)(pool + 1040);     // [128]
    float*         s_dinv  = (float*)(pool + 1552);   // [128]
    // late views (first written in phase 6a, after full barriers)
    float*         s_pm    = (float*)pool;            // [256]
    float*         s_means = (float*)(pool + 1024);   // [64]

    const int tid  = threadIdx.x;
    const int b    = blockIdx.x;
    const int wid  = tid >> 6;
    const int lane = tid & 63;
    const int l15  = lane & 15;
    const int lg   = lane >> 4;
    const long obase = (long)b * 16257;

    const bf16_t* emb_bf = ws;
    const bf16_t* hw_bf  = ws + 8192;
    const bf16_t* w1T    = ws + 16384;
    const bf16_t* w2T    = ws + 20480;

    int mi[4], mj[4];
    {
        const int* map = (const int*)(ws + WS_MAP_OFF);
        #pragma unroll
        for (int r = 0; r < 4; ++r){
            int m = map[lane*4 + r];
            mi[r] = m & 255; mj[r] = m >> 8;
        }
    }

    const int2* ei = reinterpret_cast<const int2*>(edge_index) + b*512;
    int2 e0 = ei[tid];
    int2 e1 = ei[tid + 256];

    // ---- phase 0: node ids, zero counts, biases ----
    if (tid < 128) s_nf8[tid] = (unsigned char)node_feature[b*128 + tid];
    else if (tid < 192){
        int j = tid - 128;
        s_b[j]       = gcn_b[j];
        s_b[64 + j]  = lin1_b[j];
        s_b[128 + j] = lin2_b[j];
        s_b[192 + j] = ln_g[j];
        s_b[256 + j] = ln_b[j];
        s_cur[j] = 0;                           // entries 0..63
    } else {
        s_cur[tid - 192 + 64] = 0;              // entries 64..127
    }
    __syncthreads();

    // ---- phase 1: edge count + h1 gather ----
    atomicAdd(&s_cur[e0.y & 127], 1);
    atomicAdd(&s_cur[e1.y & 127], 1);
    #pragma unroll
    for (int c = tid; c < 1024; c += 256){
        int row = c >> 3, ch = c & 7;
        uint4 vh = reinterpret_cast<const uint4*>(hw_bf + (int)s_nf8[row]*64)[ch];
        reinterpret_cast<uint4*>(&bufB[row*LDR])[ch] = vh;
    }
    __syncthreads();

    // ---- phase 2: wave0 scan (counts->start, dinv, cursor) ----
    if (tid < 64){
        int a0 = s_cur[2*tid], a1 = s_cur[2*tid+1];
        s_dinv[2*tid]   = rsqrtf((float)(a0 + 1));
        s_dinv[2*tid+1] = rsqrtf((float)(a1 + 1));
        int s = a0 + a1;
        #pragma unroll
        for (int d = 1; d < 64; d <<= 1){
            int v = __shfl_up(s, d);
            if (lane >= d) s += v;
        }
        int excl = s - (a0 + a1);
        s_start[2*tid]   = excl;
        s_start[2*tid+1] = excl + a0;
        if (tid == 63) s_start[128] = 512;
        s_cur[2*tid]   = excl;
        s_cur[2*tid+1] = excl + a0;
    }
    __syncthreads();

    // ---- phase 2c: bucket sort edges by dst (from registers) ----
    {
        int pos0 = atomicAdd(&s_cur[e0.y & 127], 1);
        s_adj[pos0] = (unsigned char)(e0.x & 127);
        int pos1 = atomicAdd(&s_cur[e1.y & 127], 1);
        s_adj[pos1] = (unsigned char)(e1.x & 127);
    }
    __syncthreads();

    // ---- phase 3+4 fused: agg in registers (A-frag layout); t = relu(agg@lin1+b1)
    {
        // thread owns rows {wid*32 + fm*16 + l15 : fm=0,1},
        // cols {kk*32 + lg*8 + e : kk=0,1; e=0..7}
        float inner[2][16];
        float dnv[2];
        #pragma unroll
        for (int fm = 0; fm < 2; ++fm)
            #pragma unroll
            for (int f = 0; f < 16; ++f) inner[fm][f] = 0.f;

        #pragma unroll
        for (int fm = 0; fm < 2; ++fm){
            const int row = wid*32 + fm*16 + l15;
            const float dn = s_dinv[row];
            dnv[fm] = dn;
            {   // self loop
                uint4 c0 = *reinterpret_cast<const uint4*>(&bufB[row*LDR + lg*8]);
                uint4 c1 = *reinterpret_cast<const uint4*>(&bufB[row*LDR + 32 + lg*8]);
                inner[fm][0]  += dn * bflo(c0.x); inner[fm][1]  += dn * bfhi(c0.x);
                inner[fm][2]  += dn * bflo(c0.y); inner[fm][3]  += dn * bfhi(c0.y);
                inner[fm][4]  += dn * bflo(c0.z); inner[fm][5]  += dn * bfhi(c0.z);
                inner[fm][6]  += dn * bflo(c0.w); inner[fm][7]  += dn * bfhi(c0.w);
                inner[fm][8]  += dn * bflo(c1.x); inner[fm][9]  += dn * bfhi(c1.x);
                inner[fm][10] += dn * bflo(c1.y); inner[fm][11] += dn * bfhi(c1.y);
                inner[fm][12] += dn * bflo(c1.z); inner[fm][13] += dn * bfhi(c1.z);
                inner[fm][14] += dn * bflo(c1.w); inner[fm][15] += dn * bfhi(c1.w);
            }
            const int st = s_start[row], cn = s_start[row+1] - st;
            for (int k = 0; k < cn; ++k){
                int src = s_adj[st + k];
                float w = s_dinv[src];
                uint4 c0 = *reinterpret_cast<const uint4*>(&bufB[src*LDR + lg*8]);
                uint4 c1 = *reinterpret_cast<const uint4*>(&bufB[src*LDR + 32 + lg*8]);
                inner[fm][0]  += w * bflo(c0.x); inner[fm][1]  += w * bfhi(c0.x);
                inner[fm][2]  += w * bflo(c0.y); inner[fm][3]  += w * bfhi(c0.y);
                inner[fm][4]  += w * bflo(c0.z); inner[fm][5]  += w * bfhi(c0.z);
                inner[fm][6]  += w * bflo(c0.w); inner[fm][7]  += w * bfhi(c0.w);
                inner[fm][8]  += w * bflo(c1.x); inner[fm][9]  += w * bfhi(c1.x);
                inner[fm][10] += w * bflo(c1.y); inner[fm][11] += w * bfhi(c1.y);
                inner[fm][12] += w * bflo(c1.z); inner[fm][13] += w * bfhi(c1.z);
                inner[fm][14] += w * bflo(c1.w); inner[fm][15] += w * bfhi(c1.w);
            }
        }

        // A-frags in registers: af[fm][kk][e] = agg[row][kk*32 + lg*8 + e]
        bf16x8 af[2][2];
        #pragma unroll
        for (int fm = 0; fm < 2; ++fm)
            #pragma unroll
            for (int kk = 0; kk < 2; ++kk)
                #pragma unroll
                for (int e = 0; e < 8; ++e){
                    int col = kk*32 + lg*8 + e;
                    af[fm][kk][e] = (bf16_t)(dnv[fm]*inner[fm][kk*8 + e] + s_b[col]);
                }

        f32x4 acc[2][4];
        #pragma unroll
        for (int fm = 0; fm < 2; ++fm)
            #pragma unroll
            for (int fn = 0; fn < 4; ++fn)
                acc[fm][fn] = (f32x4){0.f,0.f,0.f,0.f};
        #pragma unroll
        for (int fn = 0; fn < 4; ++fn)
            #pragma unroll
            for (int kk = 0; kk < 2; ++kk){
                bf16x8 bfr = *reinterpret_cast<const bf16x8*>(
                    &w1T[(fn*16 + l15)*64 + kk*32 + lg*8]);
                #pragma unroll
                for (int fm = 0; fm < 2; ++fm)
                    acc[fm][fn] = __builtin_amdgcn_mfma_f32_16x16x32_bf16(
                        af[fm][kk], bfr, acc[fm][fn], 0, 0, 0);
            }

        // all cross-wave h1 reads are done; safe to overwrite bufB with t
        __syncthreads();

        #pragma unroll
        for (int fm = 0; fm < 2; ++fm)
            #pragma unroll
            for (int fn = 0; fn < 4; ++fn)
                #pragma unroll
                for (int r = 0; r < 4; ++r){
                    int row = wid*32 + fm*16 + mi[r];
                    int col = fn*16 + mj[r];
                    bufB[row*LDR + col] = (bf16_t)fmaxf(acc[fm][fn][r] + s_b[64 + col], 0.f);
                }
    }
    lds_fence();

    // ---- phase 5 (MFMA): v = t @ lin2 + b2 -> bufB own rows ----
    {
        bf16x8 af[2][2];
        #pragma unroll
        for (int fm = 0; fm < 2; ++fm)
            #pragma unroll
            for (int kk = 0; kk < 2; ++kk)
                af[fm][kk] = *reinterpret_cast<const bf16x8*>(
                    &bufB[(wid*32 + fm*16 + l15)*LDR + kk*32 + lg*8]);
        f32x4 acc[2][4];
        #pragma unroll
        for (int fm = 0; fm < 2; ++fm)
            #pragma unroll
            for (int fn = 0; fn < 4; ++fn)
                acc[fm][fn] = (f32x4){0.f,0.f,0.f,0.f};
        #pragma unroll
        for (int fn = 0; fn < 4; ++fn)
            #pragma unroll
            for (int kk = 0; kk < 2; ++kk){
                bf16x8 bfr = *reinterpret_cast<const bf16x8*>(
                    &w2T[(fn*16 + l15)*64 + kk*32 + lg*8]);
                #pragma unroll
                for (int fm = 0; fm < 2; ++fm)
                    acc[fm][fn] = __builtin_amdgcn_mfma_f32_16x16x32_bf16(
                        af[fm][kk], bfr, acc[fm][fn], 0, 0, 0);
            }
        lds_fence();   // A-frag reads complete before overwriting with v
        #pragma unroll
        for (int fm = 0; fm < 2; ++fm)
            #pragma unroll
            for (int fn = 0; fn < 4; ++fn)
                #pragma unroll
                for (int r = 0; r < 4; ++r){
                    int row = wid*32 + fm*16 + mi[r];
                    int col = fn*16 + mj[r];
                    bufB[row*LDR + col] = (bf16_t)(acc[fm][fn][r] + s_b[128 + col]);
                }
    }
    lds_fence();

    // ---- phase 5b: ef = LN(v + x) row-owner pass (own rows) ----
    {
        const int n  = tid >> 1;
        const int f0 = (tid & 1) << 5;
        const bf16x8* xp = reinterpret_cast<const bf16x8*>(&emb_bf[(int)s_nf8[n]*64 + f0]);
        const bf16x8* rp = reinterpret_cast<const bf16x8*>(&bufB[n*LDR + f0]);
        float vv[32];
        float p1 = 0.f, p2 = 0.f;
        #pragma unroll
        for (int q = 0; q < 4; ++q){
            bf16x8 v8 = rp[q];
            bf16x8 x8 = xp[q];
            #pragma unroll
            for (int e = 0; e < 8; ++e){
                float f = (float)v8[e] + (float)x8[e];
                vv[q*8+e] = f; p1 += f; p2 += f*f;
            }
        }
        p1 += __shfl_xor(p1, 1);
        p2 += __shfl_xor(p2, 1);
        float mean = p1 * 0.015625f;
        float var  = p2 * 0.015625f - mean*mean;
        float rstd = rsqrtf(var + 1e-5f);
        #pragma unroll
        for (int j = 0; j < 32; ++j)
            bufB[n*LDR + f0 + j] = (bf16_t)((vv[j] - mean) * rstd * s_b[192 + f0 + j] + s_b[256 + f0 + j]);
    }
    __syncthreads();   // ef complete; cross-wave readers below

    // ---- phase 6a: per-graph column means of ef ----
    {
        int col = tid & 63, q = tid >> 6;
        float s = 0.f;
        #pragma unroll 8
        for (int r = q*32; r < q*32 + 32; ++r)
            s += (float)bufB[r*LDR + col];
        s_pm[q*64 + col] = s;
    }
    __syncthreads();   // s_pm visible to wave 0; ef stable for P7

    // ---- phase 6b: exit head (wave 0 only; same-wave LDS RAW needs no barrier;
    //      waves 1-3 fall straight through to P7) ----
    if (tid < 64){
        s_means[tid] = (s_pm[tid] + s_pm[64+tid] + s_pm[128+tid] + s_pm[192+tid]) * 0.0078125f;
        float a = ex_b1[lane];
        #pragma unroll 8
        for (int k = 0; k < 64; ++k)
            a += s_means[k] * ex_w1[k*64 + lane];
        float p1 = a, p2 = a*a;
        #pragma unroll
        for (int m = 1; m < 64; m <<= 1){ p1 += __shfl_xor(p1, m); p2 += __shfl_xor(p2, m); }
        float mean = p1 * 0.015625f;
        float var  = p2 * 0.015625f - mean*mean;
        float u = (a - mean) * rsqrtf(var + 1e-5f) * ex_ln_g[lane] + ex_ln_b[lane];
        u = fmaxf(u, 0.f);
        float prod = u * ex_w2[lane];
        #pragma unroll
        for (int m = 1; m < 64; m <<= 1) prod += __shfl_xor(prod, m);
        if (lane == 0) out[obase + 16256] = prod + ex_b2[0];
    }

    // ---- phase 7: scores = ef @ ef^T / 8 (MFMA), scalar triu/tril scatter ----
    {
        bf16x8 af[2][2];
        #pragma unroll
        for (int fm = 0; fm < 2; ++fm)
            #pragma unroll
            for (int kk = 0; kk < 2; ++kk)
                af[fm][kk] = *reinterpret_cast<const bf16x8*>(
                    &bufB[(wid*32 + fm*16 + l15)*LDR + kk*32 + lg*8]);
        f32x4 acc[2][8];
        #pragma unroll
        for (int fm = 0; fm < 2; ++fm)
            #pragma unroll
            for (int fn = 0; fn < 8; ++fn)
                acc[fm][fn] = (f32x4){0.f,0.f,0.f,0.f};
        #pragma unroll
        for (int fn = 0; fn < 8; ++fn)
            #pragma unroll
            for (int kk = 0; kk < 2; ++kk){
                bf16x8 bfr = *reinterpret_cast<const bf16x8*>(
                    &bufB[(fn*16 + l15)*LDR + kk*32 + lg*8]);
                #pragma unroll
                for (int fm = 0; fm < 2; ++fm)
                    acc[fm][fn] = __builtin_amdgcn_mfma_f32_16x16x32_bf16(
                        af[fm][kk], bfr, acc[fm][fn], 0, 0, 0);
            }
        float* ob = out + obase;
        #pragma unroll
        for (int fm = 0; fm < 2; ++fm){
            #pragma unroll
            for (int fn = 0; fn < 8; ++fn){
                #pragma unroll
                for (int r = 0; r < 4; ++r){
                    int i = wid*32 + fm*16 + mi[r];
                    int j = fn*16 + mj[r];
                    if (i != j){
                        float v = acc[fm][fn][r] * 0.125f;
                        int p = (i < j) ? (i*127 - ((i*(i-1)) >> 1) + j - i - 1)
                                        : (8128 + ((i*(i-1)) >> 1) + j);
                        ob[p] = v;
                    }
                }
            }
        }
    }
}

extern "C" void kernel_launch(void* const* d_in, const int* in_sizes, int n_in,
                              void* d_out, int out_size, void* d_ws, size_t ws_size,
                              hipStream_t stream)
{
    const int*   node_feature = (const int*)  d_in[0];
    const int*   edge_index   = (const int*)  d_in[1];
    // d_in[2] = batch_ptr (uniform arange*128, unused)
    const float* emb     = (const float*)d_in[3];
    const float* gcn_w   = (const float*)d_in[4];
    const float* gcn_b   = (const float*)d_in[5];
    const float* lin1_w  = (const float*)d_in[6];
    const float* lin1_b  = (const float*)d_in[7];
    const float* lin2_w  = (const float*)d_in[8];
    const float* lin2_b  = (const float*)d_in[9];
    const float* ln_g    = (const float*)d_in[10];
    const float* ln_b    = (const float*)d_in[11];
    const float* ex_w1   = (const float*)d_in[12];
    const float* ex_b1   = (const float*)d_in[13];
    const float* ex_ln_g = (const float*)d_in[14];
    const float* ex_ln_b = (const float*)d_in[15];
    const float* ex_w2   = (const float*)d_in[16];
    const float* ex_b2   = (const float*)d_in[17];
    bf16_t* ws  = (bf16_t*)d_ws;
    float*  out = (float*)d_out;

    prep_kernel<<<32, 256, 0, stream>>>(emb, gcn_w, lin1_w, lin2_w, ws);
    fused_kernel<<<2048, 256, 0, stream>>>(node_feature, edge_index,
        gcn_b, lin1_b, lin2_b, ln_g, ln_b,
        ex_w1, ex_b1, ex_ln_g, ex_ln_b, ex_w2, ex_b2,
        ws, out);
}